// Round 2
// baseline (5872.823 us; speedup 1.0000x reference)
//
#include <hip/hip_runtime.h>
#include <math.h>

#define B_ 2
#define T_ 1024
#define D_ 512
#define H_ 8
#define HD_ 64
#define F_ 2048
#define L_ 2
#define V_ 32000
#define M_ (B_*T_)
#define EPS_ 1e-5f

// ---------------------------------------------------------------------------
// Embedding + sinusoidal positional encoding: y[row,d] = emb[tok[row],d]+pe(t,d)
// ---------------------------------------------------------------------------
__global__ __launch_bounds__(256) void embed_kernel(const int* __restrict__ tok,
                                                    const float* __restrict__ emb,
                                                    float* __restrict__ y)
{
    int idx = blockIdx.x * 256 + threadIdx.x;      // over M_*D_
    int d   = idx & (D_ - 1);
    int row = idx >> 9;                            // /D_
    int t   = row & (T_ - 1);
    int token = tok[row];
    float arg = (float)t / powf(10000.f, (float)(d & ~1) / (float)D_);
    float pe  = (d & 1) ? cosf(arg) : sinf(arg);
    y[idx] = emb[(size_t)token * D_ + d] + pe;
}

// ---------------------------------------------------------------------------
// fp32 GEMM: C[M,N] = A[M,K] @ W[K,N] + bias[N]  (optional fused ReLU)
// 128x128 tile, BK=16, 256 threads, 8x8 per-thread microtile.
// All call sites: M%128==0, N%128==0, K%16==0.
// ---------------------------------------------------------------------------
template<int RELU>
__global__ __launch_bounds__(256) void gemm_kernel(const float* __restrict__ A,
                                                   const float* __restrict__ W,
                                                   const float* __restrict__ bias,
                                                   float* __restrict__ C,
                                                   int M, int N, int K)
{
    const int BM = 128, BN = 128, BK = 16;
    __shared__ float As[BK][BM];
    __shared__ float Bs[BK][BN + 4];
    int tid = threadIdx.x;
    int tx = tid & 15, ty = tid >> 4;
    int brow = blockIdx.y * BM, bcol = blockIdx.x * BN;

    float acc[8][8] = {};

    for (int kt = 0; kt < K; kt += BK) {
        // A tile: 128 rows x 16 cols, transposed into LDS
        #pragma unroll
        for (int l = 0; l < 2; ++l) {
            int f = tid + l * 256;
            int r = f >> 2, kq = (f & 3) << 2;
            float4 v = *(const float4*)&A[(size_t)(brow + r) * K + kt + kq];
            As[kq + 0][r] = v.x; As[kq + 1][r] = v.y;
            As[kq + 2][r] = v.z; As[kq + 3][r] = v.w;
        }
        // B tile: 16 rows x 128 cols
        #pragma unroll
        for (int l = 0; l < 2; ++l) {
            int f = tid + l * 256;
            int kr = f >> 5, nq = (f & 31) << 2;
            float4 v = *(const float4*)&W[(size_t)(kt + kr) * N + bcol + nq];
            *(float4*)&Bs[kr][nq] = v;
        }
        __syncthreads();
        #pragma unroll
        for (int k = 0; k < BK; ++k) {
            float a[8], b[8];
            #pragma unroll
            for (int i = 0; i < 8; ++i) a[i] = As[k][ty * 8 + i];
            #pragma unroll
            for (int j = 0; j < 8; ++j) b[j] = Bs[k][tx * 8 + j];
            #pragma unroll
            for (int i = 0; i < 8; ++i)
                #pragma unroll
                for (int j = 0; j < 8; ++j)
                    acc[i][j] = fmaf(a[i], b[j], acc[i][j]);
        }
        __syncthreads();
    }

    // epilogue: vectorized bias add + store (two float4 per row)
    float4 bv0 = *(const float4*)&bias[bcol + tx * 8];
    float4 bv1 = *(const float4*)&bias[bcol + tx * 8 + 4];
    #pragma unroll
    for (int i = 0; i < 8; ++i) {
        int r = brow + ty * 8 + i;
        float4 o0, o1;
        o0.x = acc[i][0] + bv0.x; o0.y = acc[i][1] + bv0.y;
        o0.z = acc[i][2] + bv0.z; o0.w = acc[i][3] + bv0.w;
        o1.x = acc[i][4] + bv1.x; o1.y = acc[i][5] + bv1.y;
        o1.z = acc[i][6] + bv1.z; o1.w = acc[i][7] + bv1.w;
        if (RELU) {
            o0.x = fmaxf(o0.x, 0.f); o0.y = fmaxf(o0.y, 0.f);
            o0.z = fmaxf(o0.z, 0.f); o0.w = fmaxf(o0.w, 0.f);
            o1.x = fmaxf(o1.x, 0.f); o1.y = fmaxf(o1.y, 0.f);
            o1.z = fmaxf(o1.z, 0.f); o1.w = fmaxf(o1.w, 0.f);
        }
        *(float4*)&C[(size_t)r * N + bcol + tx * 8]     = o0;
        *(float4*)&C[(size_t)r * N + bcol + tx * 8 + 4] = o1;
    }
}

// ---------------------------------------------------------------------------
// Attention: one block (256 thr) per (b, h, q-row). Scores over T_=1024 keys
// in LDS, block softmax, then PV. Generic over buffer layouts via ld/offset.
// out[qrow, h*HD_+d] (a-buffer, stride D_)
// ---------------------------------------------------------------------------
__global__ __launch_bounds__(256) void attn_kernel(
    const float* __restrict__ Q, int qld, int qoff,
    const float* __restrict__ Kb, int kld, int koff,
    const float* __restrict__ Vb, int vld, int voff,
    const float* __restrict__ mask, float* __restrict__ out)
{
    __shared__ float s[T_];
    __shared__ float qs[HD_];
    __shared__ float red[256];
    __shared__ float part[4][HD_];

    int tid = threadIdx.x;
    int qt = blockIdx.x & (T_ - 1);
    int h  = (blockIdx.x >> 10) & (H_ - 1);
    int b  = blockIdx.x >> 13;
    int qrow = b * T_ + qt;

    if (tid < HD_) qs[tid] = Q[(size_t)qrow * qld + qoff + h * HD_ + tid];
    __syncthreads();

    // ---- scores: each thread does 4 keys
    float lmax = -1e30f;
    #pragma unroll
    for (int c = 0; c < 4; ++c) {
        int kt = tid + c * 256;
        const float* kp = &Kb[(size_t)(b * T_ + kt) * kld + koff + h * HD_];
        float acc = 0.f;
        #pragma unroll
        for (int d = 0; d < HD_; d += 4) {
            float4 kv = *(const float4*)&kp[d];
            float4 qv = *(const float4*)&qs[d];
            acc = fmaf(qv.x, kv.x, acc); acc = fmaf(qv.y, kv.y, acc);
            acc = fmaf(qv.z, kv.z, acc); acc = fmaf(qv.w, kv.w, acc);
        }
        acc = acc * 0.125f + mask[(size_t)b * T_ * T_ + (size_t)qt * T_ + kt];
        s[kt] = acc;
        lmax = fmaxf(lmax, acc);
    }
    // ---- block max
    red[tid] = lmax; __syncthreads();
    for (int st = 128; st > 0; st >>= 1) {
        if (tid < st) red[tid] = fmaxf(red[tid], red[tid + st]);
        __syncthreads();
    }
    float mx = red[0];
    __syncthreads();
    // ---- exp + block sum
    float lsum = 0.f;
    #pragma unroll
    for (int c = 0; c < 4; ++c) {
        int kt = tid + c * 256;
        float p = expf(s[kt] - mx);
        s[kt] = p;
        lsum += p;
    }
    red[tid] = lsum; __syncthreads();
    for (int st = 128; st > 0; st >>= 1) {
        if (tid < st) red[tid] += red[tid + st];
        __syncthreads();
    }
    float inv = 1.f / red[0];
    __syncthreads();

    // ---- PV: 4 groups of 64 lanes; lane d accumulates 256 keys
    int d = tid & (HD_ - 1);
    int grp = tid >> 6;
    float accv = 0.f;
    for (int kk = 0; kk < 256; ++kk) {
        int kt = grp * 256 + kk;
        accv = fmaf(s[kt], Vb[(size_t)(b * T_ + kt) * vld + voff + h * HD_ + d], accv);
    }
    part[grp][d] = accv;
    __syncthreads();
    if (tid < HD_) {
        float o = (part[0][tid] + part[1][tid] + part[2][tid] + part[3][tid]) * inv;
        out[(size_t)qrow * D_ + h * HD_ + tid] = o;
    }
}

// ---------------------------------------------------------------------------
// Fused residual-add + LayerNorm: out = LN(a + r) * g + be. One block per row.
// ---------------------------------------------------------------------------
__global__ __launch_bounds__(256) void ln_kernel(const float* __restrict__ a,
                                                 const float* __restrict__ r,
                                                 const float* __restrict__ g,
                                                 const float* __restrict__ be,
                                                 float* __restrict__ out)
{
    __shared__ float red[256], red2[256];
    int row = blockIdx.x;
    int tid = threadIdx.x;
    size_t base = (size_t)row * D_;
    float v0 = a[base + tid]       + r[base + tid];
    float v1 = a[base + tid + 256] + r[base + tid + 256];
    red[tid] = v0 + v1;
    red2[tid] = v0 * v0 + v1 * v1;
    __syncthreads();
    for (int st = 128; st > 0; st >>= 1) {
        if (tid < st) { red[tid] += red[tid + st]; red2[tid] += red2[tid + st]; }
        __syncthreads();
    }
    float mean = red[0] * (1.f / D_);
    float var  = red2[0] * (1.f / D_) - mean * mean;
    float rstd = rsqrtf(var + EPS_);
    out[base + tid]       = (v0 - mean) * rstd * g[tid]       + be[tid];
    out[base + tid + 256] = (v1 - mean) * rstd * g[tid + 256] + be[tid + 256];
}

// ---------------------------------------------------------------------------
// Workspace layout (floats), total 7M floats = 28 MB:
//   y    = ws + 0        [M, D]   persistent activation
//   tmp  = ws + 1M       [M, D]   pre-LN buffer
//   abuf = ws + 2M       [M, D]   attention output
//   big  = ws + 3M       [M, 2048] shared: qkv(3D) | kv(2D)+q(D) | ffn(F)
// ---------------------------------------------------------------------------
extern "C" void kernel_launch(void* const* d_in, const int* in_sizes, int n_in,
                              void* d_out, int out_size, void* d_ws, size_t ws_size,
                              hipStream_t stream)
{
    const float* x          = (const float*)d_in[0];
    const int*   y_tokens   = (const int*)  d_in[1];
    const float* self_mask  = (const float*)d_in[2];
    const float* cross_mask = (const float*)d_in[3];
    const float* emb        = (const float*)d_in[4];
    const float* Wqkv = (const float*)d_in[5];  const float* bqkv = (const float*)d_in[6];
    const float* Wo   = (const float*)d_in[7];  const float* bo   = (const float*)d_in[8];
    const float* Wkv  = (const float*)d_in[9];  const float* bkv  = (const float*)d_in[10];
    const float* Wq   = (const float*)d_in[11]; const float* bq   = (const float*)d_in[12];
    const float* Wco  = (const float*)d_in[13]; const float* bco  = (const float*)d_in[14];
    const float* W1   = (const float*)d_in[15]; const float* b1   = (const float*)d_in[16];
    const float* W2   = (const float*)d_in[17]; const float* b2   = (const float*)d_in[18];
    const float* g1   = (const float*)d_in[19]; const float* be1  = (const float*)d_in[20];
    const float* g2   = (const float*)d_in[21]; const float* be2  = (const float*)d_in[22];
    const float* g3   = (const float*)d_in[23]; const float* be3  = (const float*)d_in[24];

    float* ws = (float*)d_ws;
    const size_t MD = (size_t)M_ * D_;        // 1M floats
    float* y    = ws;                         // [M, D]
    float* tmp  = ws + MD;                    // [M, D]
    float* abuf = ws + 2 * MD;                // [M, D]
    float* big  = ws + 3 * MD;                // [M, 4D] shared region
    float* qb   = big + 2 * MD;               // cross-attn Q lives after kv

    // y = emb[tokens] + pos_enc
    embed_kernel<<<(M_ * D_) / 256, 256, 0, stream>>>(y_tokens, emb, y);

    for (int l = 0; l < L_; ++l) {
        const float* Wqkv_l = Wqkv + (size_t)l * D_ * 3 * D_;
        const float* bqkv_l = bqkv + (size_t)l * 3 * D_;
        const float* Wo_l   = Wo   + (size_t)l * D_ * D_;
        const float* bo_l   = bo   + (size_t)l * D_;
        const float* Wkv_l  = Wkv  + (size_t)l * D_ * 2 * D_;
        const float* bkv_l  = bkv  + (size_t)l * 2 * D_;
        const float* Wq_l   = Wq   + (size_t)l * D_ * D_;
        const float* bq_l   = bq   + (size_t)l * D_;
        const float* Wco_l  = Wco  + (size_t)l * D_ * D_;
        const float* bco_l  = bco  + (size_t)l * D_;
        const float* W1_l   = W1   + (size_t)l * D_ * F_;
        const float* b1_l   = b1   + (size_t)l * F_;
        const float* W2_l   = W2   + (size_t)l * F_ * D_;
        const float* b2_l   = b2   + (size_t)l * D_;

        // ---- self-attention block
        gemm_kernel<0><<<dim3(3 * D_ / 128, M_ / 128), 256, 0, stream>>>(
            y, Wqkv_l, bqkv_l, big, M_, 3 * D_, D_);
        attn_kernel<<<B_ * H_ * T_, 256, 0, stream>>>(
            big, 3 * D_, 0, big, 3 * D_, D_, big, 3 * D_, 2 * D_, self_mask, abuf);
        gemm_kernel<0><<<dim3(D_ / 128, M_ / 128), 256, 0, stream>>>(
            abuf, Wo_l, bo_l, tmp, M_, D_, D_);
        ln_kernel<<<M_, 256, 0, stream>>>(tmp, y, g1 + l * D_, be1 + l * D_, y);

        // ---- cross-attention block (K,V from encoder output x)
        gemm_kernel<0><<<dim3(2 * D_ / 128, M_ / 128), 256, 0, stream>>>(
            x, Wkv_l, bkv_l, big, M_, 2 * D_, D_);
        gemm_kernel<0><<<dim3(D_ / 128, M_ / 128), 256, 0, stream>>>(
            y, Wq_l, bq_l, qb, M_, D_, D_);
        attn_kernel<<<B_ * H_ * T_, 256, 0, stream>>>(
            qb, D_, 0, big, 2 * D_, 0, big, 2 * D_, D_, cross_mask, abuf);
        gemm_kernel<0><<<dim3(D_ / 128, M_ / 128), 256, 0, stream>>>(
            abuf, Wco_l, bco_l, tmp, M_, D_, D_);
        ln_kernel<<<M_, 256, 0, stream>>>(tmp, y, g2 + l * D_, be2 + l * D_, y);

        // ---- feed-forward block
        gemm_kernel<1><<<dim3(F_ / 128, M_ / 128), 256, 0, stream>>>(
            y, W1_l, b1_l, big, M_, F_, D_);
        gemm_kernel<0><<<dim3(D_ / 128, M_ / 128), 256, 0, stream>>>(
            big, W2_l, b2_l, tmp, M_, D_, F_);
        float* lnout = (l == L_ - 1) ? (float*)d_out : y;
        ln_kernel<<<M_, 256, 0, stream>>>(tmp, y, g3 + l * D_, be3 + l * D_, lnout);
    }
}

// Round 3
// 1927.014 us; speedup vs baseline: 3.0476x; 3.0476x over previous
//
#include <hip/hip_runtime.h>
#include <math.h>

#define B_ 2
#define T_ 1024
#define D_ 512
#define H_ 8
#define HD_ 64
#define F_ 2048
#define L_ 2
#define V_ 32000
#define M_ (B_*T_)
#define EPS_ 1e-5f

// ---------------------------------------------------------------------------
// Embedding + sinusoidal positional encoding
// ---------------------------------------------------------------------------
__global__ __launch_bounds__(256) void embed_kernel(const int* __restrict__ tok,
                                                    const float* __restrict__ emb,
                                                    float* __restrict__ y)
{
    int idx = blockIdx.x * 256 + threadIdx.x;      // over M_*D_
    int d   = idx & (D_ - 1);
    int row = idx >> 9;                            // /D_
    int t   = row & (T_ - 1);
    int token = tok[row];
    float arg = (float)t / powf(10000.f, (float)(d & ~1) / (float)D_);
    float pe  = (d & 1) ? cosf(arg) : sinf(arg);
    y[idx] = emb[(size_t)token * D_ + d] + pe;
}

// ---------------------------------------------------------------------------
// fp32 GEMM: C[M,N] = A[M,K] @ W[K,N] + bias (optional ReLU). 128x128 tile.
// ---------------------------------------------------------------------------
template<int RELU>
__global__ __launch_bounds__(256) void gemm_kernel(const float* __restrict__ A,
                                                   const float* __restrict__ W,
                                                   const float* __restrict__ bias,
                                                   float* __restrict__ C,
                                                   int M, int N, int K)
{
    const int BM = 128, BN = 128, BK = 16;
    __shared__ float As[BK][BM];
    __shared__ float Bs[BK][BN + 4];
    int tid = threadIdx.x;
    int tx = tid & 15, ty = tid >> 4;
    int brow = blockIdx.y * BM, bcol = blockIdx.x * BN;

    float acc[8][8] = {};

    for (int kt = 0; kt < K; kt += BK) {
        #pragma unroll
        for (int l = 0; l < 2; ++l) {
            int f = tid + l * 256;
            int r = f >> 2, kq = (f & 3) << 2;
            float4 v = *(const float4*)&A[(size_t)(brow + r) * K + kt + kq];
            As[kq + 0][r] = v.x; As[kq + 1][r] = v.y;
            As[kq + 2][r] = v.z; As[kq + 3][r] = v.w;
        }
        #pragma unroll
        for (int l = 0; l < 2; ++l) {
            int f = tid + l * 256;
            int kr = f >> 5, nq = (f & 31) << 2;
            float4 v = *(const float4*)&W[(size_t)(kt + kr) * N + bcol + nq];
            *(float4*)&Bs[kr][nq] = v;
        }
        __syncthreads();
        #pragma unroll
        for (int k = 0; k < BK; ++k) {
            float a[8], b[8];
            #pragma unroll
            for (int i = 0; i < 8; ++i) a[i] = As[k][ty * 8 + i];
            #pragma unroll
            for (int j = 0; j < 8; ++j) b[j] = Bs[k][tx * 8 + j];
            #pragma unroll
            for (int i = 0; i < 8; ++i)
                #pragma unroll
                for (int j = 0; j < 8; ++j)
                    acc[i][j] = fmaf(a[i], b[j], acc[i][j]);
        }
        __syncthreads();
    }

    float4 bv0 = *(const float4*)&bias[bcol + tx * 8];
    float4 bv1 = *(const float4*)&bias[bcol + tx * 8 + 4];
    #pragma unroll
    for (int i = 0; i < 8; ++i) {
        int r = brow + ty * 8 + i;
        float4 o0, o1;
        o0.x = acc[i][0] + bv0.x; o0.y = acc[i][1] + bv0.y;
        o0.z = acc[i][2] + bv0.z; o0.w = acc[i][3] + bv0.w;
        o1.x = acc[i][4] + bv1.x; o1.y = acc[i][5] + bv1.y;
        o1.z = acc[i][6] + bv1.z; o1.w = acc[i][7] + bv1.w;
        if (RELU) {
            o0.x = fmaxf(o0.x, 0.f); o0.y = fmaxf(o0.y, 0.f);
            o0.z = fmaxf(o0.z, 0.f); o0.w = fmaxf(o0.w, 0.f);
            o1.x = fmaxf(o1.x, 0.f); o1.y = fmaxf(o1.y, 0.f);
            o1.z = fmaxf(o1.z, 0.f); o1.w = fmaxf(o1.w, 0.f);
        }
        *(float4*)&C[(size_t)r * N + bcol + tx * 8]     = o0;
        *(float4*)&C[(size_t)r * N + bcol + tx * 8 + 4] = o1;
    }
}

// ---------------------------------------------------------------------------
// Flash attention (fp32, VALU). Block = 512 thr = 8 waves handles a 64-q-row
// tile for one (b,h). K/V staged in LDS per 64-key step; online softmax via
// intra-wave shfl (row's 16 contributor lanes are consecutive in one wave).
// LDS: 3 x 64x64 f32, XOR-swizzled (addr ^= ((major&7)<<2)) = 48 KB.
// Thread (tx=tid&15, ty=tid>>4) owns rows q=2ty+{0,1}, cols 4tx+{0..3}.
// ---------------------------------------------------------------------------
__global__ __launch_bounds__(512) void fattn_kernel(
    const float* __restrict__ Q, int qld, int qoff,
    const float* __restrict__ Kb, int kld, int koff,
    const float* __restrict__ Vb, int vld, int voff,
    const float* __restrict__ mask, float* __restrict__ out)
{
    __shared__ float Qs[HD_][64];   // [d][q ^ ((d&7)<<2)]
    __shared__ float Ks[HD_][64];   // [d][k ^ ((d&7)<<2)]
    __shared__ float Vs[64][HD_];   // [k][d ^ ((k&7)<<2)]

    const int tid = threadIdx.x;
    const int tx = tid & 15, ty = tid >> 4;
    const int qbase = blockIdx.x * 64;
    const int h = blockIdx.y, b = blockIdx.z;
    const int hoff = h * HD_;

    // ---- stage Q tile, transposed + swizzled (once)
    #pragma unroll
    for (int l = 0; l < 2; ++l) {
        int id = tid + l * 512;
        int qr = id >> 4, dq = id & 15;
        float4 v = *(const float4*)&Q[(size_t)(b * T_ + qbase + qr) * qld + qoff + hoff + 4 * dq];
        { int d = 4 * dq;     Qs[d][qr ^ ((d & 7) << 2)] = v.x; }
        { int d = 4 * dq + 1; Qs[d][qr ^ ((d & 7) << 2)] = v.y; }
        { int d = 4 * dq + 2; Qs[d][qr ^ ((d & 7) << 2)] = v.z; }
        { int d = 4 * dq + 3; Qs[d][qr ^ ((d & 7) << 2)] = v.w; }
    }

    float m0 = -1e30f, m1 = -1e30f, l0 = 0.f, l1 = 0.f;
    float o0[4] = {0.f, 0.f, 0.f, 0.f}, o1[4] = {0.f, 0.f, 0.f, 0.f};

    for (int kt = 0; kt < T_ / 64; ++kt) {
        const int k0 = kt * 64;
        __syncthreads();   // previous tile fully consumed (also covers Qs on kt=0)

        // ---- stage K (transposed+swizzled) and V (natural+swizzled)
        #pragma unroll
        for (int l = 0; l < 2; ++l) {
            int id = tid + l * 512;
            int kr = id >> 4, dq = id & 15;
            float4 kv = *(const float4*)&Kb[(size_t)(b * T_ + k0 + kr) * kld + koff + hoff + 4 * dq];
            float4 vv = *(const float4*)&Vb[(size_t)(b * T_ + k0 + kr) * vld + voff + hoff + 4 * dq];
            { int d = 4 * dq;     Ks[d][kr ^ ((d & 7) << 2)] = kv.x; }
            { int d = 4 * dq + 1; Ks[d][kr ^ ((d & 7) << 2)] = kv.y; }
            { int d = 4 * dq + 2; Ks[d][kr ^ ((d & 7) << 2)] = kv.z; }
            { int d = 4 * dq + 3; Ks[d][kr ^ ((d & 7) << 2)] = kv.w; }
            *(float4*)&Vs[kr][(4 * dq) ^ ((kr & 7) << 2)] = vv;
        }
        // mask tile regs (consumed after S compute)
        const size_t mbase = (size_t)b * T_ * T_ + (size_t)(qbase + 2 * ty) * T_ + k0 + 4 * tx;
        float4 mk0 = *(const float4*)&mask[mbase];
        float4 mk1 = *(const float4*)&mask[mbase + T_];
        __syncthreads();   // tiles ready

        // ---- S = Q K^T (2x4 microtile per thread over d)
        float s0[4] = {0.f, 0.f, 0.f, 0.f}, s1[4] = {0.f, 0.f, 0.f, 0.f};
        #pragma unroll 8
        for (int d = 0; d < HD_; ++d) {
            int sw = (d & 7) << 2;
            float2 a = *(const float2*)&Qs[d][(2 * ty) ^ sw];
            float4 bb = *(const float4*)&Ks[d][(4 * tx) ^ sw];
            s0[0] = fmaf(a.x, bb.x, s0[0]); s0[1] = fmaf(a.x, bb.y, s0[1]);
            s0[2] = fmaf(a.x, bb.z, s0[2]); s0[3] = fmaf(a.x, bb.w, s0[3]);
            s1[0] = fmaf(a.y, bb.x, s1[0]); s1[1] = fmaf(a.y, bb.y, s1[1]);
            s1[2] = fmaf(a.y, bb.z, s1[2]); s1[3] = fmaf(a.y, bb.w, s1[3]);
        }
        s0[0] = fmaf(s0[0], 0.125f, mk0.x); s0[1] = fmaf(s0[1], 0.125f, mk0.y);
        s0[2] = fmaf(s0[2], 0.125f, mk0.z); s0[3] = fmaf(s0[3], 0.125f, mk0.w);
        s1[0] = fmaf(s1[0], 0.125f, mk1.x); s1[1] = fmaf(s1[1], 0.125f, mk1.y);
        s1[2] = fmaf(s1[2], 0.125f, mk1.z); s1[3] = fmaf(s1[3], 0.125f, mk1.w);

        // ---- online softmax (row reduce over 16 consecutive lanes, shfl_xor)
        {
            float pm = fmaxf(fmaxf(s0[0], s0[1]), fmaxf(s0[2], s0[3]));
            pm = fmaxf(pm, __shfl_xor(pm, 1)); pm = fmaxf(pm, __shfl_xor(pm, 2));
            pm = fmaxf(pm, __shfl_xor(pm, 4)); pm = fmaxf(pm, __shfl_xor(pm, 8));
            float mn = fmaxf(m0, pm);
            float sc = __expf(m0 - mn);
            float rs = 0.f;
            s0[0] = __expf(s0[0] - mn); rs += s0[0];
            s0[1] = __expf(s0[1] - mn); rs += s0[1];
            s0[2] = __expf(s0[2] - mn); rs += s0[2];
            s0[3] = __expf(s0[3] - mn); rs += s0[3];
            rs += __shfl_xor(rs, 1); rs += __shfl_xor(rs, 2);
            rs += __shfl_xor(rs, 4); rs += __shfl_xor(rs, 8);
            l0 = l0 * sc + rs; m0 = mn;
            o0[0] *= sc; o0[1] *= sc; o0[2] *= sc; o0[3] *= sc;
        }
        {
            float pm = fmaxf(fmaxf(s1[0], s1[1]), fmaxf(s1[2], s1[3]));
            pm = fmaxf(pm, __shfl_xor(pm, 1)); pm = fmaxf(pm, __shfl_xor(pm, 2));
            pm = fmaxf(pm, __shfl_xor(pm, 4)); pm = fmaxf(pm, __shfl_xor(pm, 8));
            float mn = fmaxf(m1, pm);
            float sc = __expf(m1 - mn);
            float rs = 0.f;
            s1[0] = __expf(s1[0] - mn); rs += s1[0];
            s1[1] = __expf(s1[1] - mn); rs += s1[1];
            s1[2] = __expf(s1[2] - mn); rs += s1[2];
            s1[3] = __expf(s1[3] - mn); rs += s1[3];
            rs += __shfl_xor(rs, 1); rs += __shfl_xor(rs, 2);
            rs += __shfl_xor(rs, 4); rs += __shfl_xor(rs, 8);
            l1 = l1 * sc + rs; m1 = mn;
            o1[0] *= sc; o1[1] *= sc; o1[2] *= sc; o1[3] *= sc;
        }

        // ---- O += P @ V ; P redistributed by intra-wave shfl from row owners
        #pragma unroll 4
        for (int kq = 0; kq < 16; ++kq) {
            int src = (tid & 48) | kq;
            #pragma unroll
            for (int j = 0; j < 4; ++j) {
                float p0 = __shfl(s0[j], src, 64);
                float p1 = __shfl(s1[j], src, 64);
                int k = 4 * kq + j;
                int sw = (k & 7) << 2;
                float4 vv = *(const float4*)&Vs[k][(4 * tx) ^ sw];
                o0[0] = fmaf(p0, vv.x, o0[0]); o0[1] = fmaf(p0, vv.y, o0[1]);
                o0[2] = fmaf(p0, vv.z, o0[2]); o0[3] = fmaf(p0, vv.w, o0[3]);
                o1[0] = fmaf(p1, vv.x, o1[0]); o1[1] = fmaf(p1, vv.y, o1[1]);
                o1[2] = fmaf(p1, vv.z, o1[2]); o1[3] = fmaf(p1, vv.w, o1[3]);
            }
        }
    }

    // ---- epilogue: normalize and store
    float inv0 = 1.f / l0, inv1 = 1.f / l1;
    float4 r0, r1;
    r0.x = o0[0] * inv0; r0.y = o0[1] * inv0; r0.z = o0[2] * inv0; r0.w = o0[3] * inv0;
    r1.x = o1[0] * inv1; r1.y = o1[1] * inv1; r1.z = o1[2] * inv1; r1.w = o1[3] * inv1;
    size_t obase = (size_t)(b * T_ + qbase + 2 * ty) * D_ + hoff + 4 * tx;
    *(float4*)&out[obase]      = r0;
    *(float4*)&out[obase + D_] = r1;
}

// ---------------------------------------------------------------------------
// Fused residual-add + LayerNorm
// ---------------------------------------------------------------------------
__global__ __launch_bounds__(256) void ln_kernel(const float* __restrict__ a,
                                                 const float* __restrict__ r,
                                                 const float* __restrict__ g,
                                                 const float* __restrict__ be,
                                                 float* __restrict__ out)
{
    __shared__ float red[256], red2[256];
    int row = blockIdx.x;
    int tid = threadIdx.x;
    size_t base = (size_t)row * D_;
    float v0 = a[base + tid]       + r[base + tid];
    float v1 = a[base + tid + 256] + r[base + tid + 256];
    red[tid] = v0 + v1;
    red2[tid] = v0 * v0 + v1 * v1;
    __syncthreads();
    for (int st = 128; st > 0; st >>= 1) {
        if (tid < st) { red[tid] += red[tid + st]; red2[tid] += red2[tid + st]; }
        __syncthreads();
    }
    float mean = red[0] * (1.f / D_);
    float var  = red2[0] * (1.f / D_) - mean * mean;
    float rstd = rsqrtf(var + EPS_);
    out[base + tid]       = (v0 - mean) * rstd * g[tid]       + be[tid];
    out[base + tid + 256] = (v1 - mean) * rstd * g[tid + 256] + be[tid + 256];
}

// ---------------------------------------------------------------------------
extern "C" void kernel_launch(void* const* d_in, const int* in_sizes, int n_in,
                              void* d_out, int out_size, void* d_ws, size_t ws_size,
                              hipStream_t stream)
{
    const float* x          = (const float*)d_in[0];
    const int*   y_tokens   = (const int*)  d_in[1];
    const float* self_mask  = (const float*)d_in[2];
    const float* cross_mask = (const float*)d_in[3];
    const float* emb        = (const float*)d_in[4];
    const float* Wqkv = (const float*)d_in[5];  const float* bqkv = (const float*)d_in[6];
    const float* Wo   = (const float*)d_in[7];  const float* bo   = (const float*)d_in[8];
    const float* Wkv  = (const float*)d_in[9];  const float* bkv  = (const float*)d_in[10];
    const float* Wq   = (const float*)d_in[11]; const float* bq   = (const float*)d_in[12];
    const float* Wco  = (const float*)d_in[13]; const float* bco  = (const float*)d_in[14];
    const float* W1   = (const float*)d_in[15]; const float* b1   = (const float*)d_in[16];
    const float* W2   = (const float*)d_in[17]; const float* b2   = (const float*)d_in[18];
    const float* g1   = (const float*)d_in[19]; const float* be1  = (const float*)d_in[20];
    const float* g2   = (const float*)d_in[21]; const float* be2  = (const float*)d_in[22];
    const float* g3   = (const float*)d_in[23]; const float* be3  = (const float*)d_in[24];

    float* ws = (float*)d_ws;
    const size_t MD = (size_t)M_ * D_;        // 1M floats
    float* y    = ws;                         // [M, D]
    float* tmp  = ws + MD;                    // [M, D]
    float* abuf = ws + 2 * MD;                // [M, D]
    float* big  = ws + 3 * MD;                // [M, 4D] shared: qkv | kv+q | ffn
    float* qb   = big + 2 * MD;               // cross-attn Q after kv

    embed_kernel<<<(M_ * D_) / 256, 256, 0, stream>>>(y_tokens, emb, y);

    for (int l = 0; l < L_; ++l) {
        const float* Wqkv_l = Wqkv + (size_t)l * D_ * 3 * D_;
        const float* bqkv_l = bqkv + (size_t)l * 3 * D_;
        const float* Wo_l   = Wo   + (size_t)l * D_ * D_;
        const float* bo_l   = bo   + (size_t)l * D_;
        const float* Wkv_l  = Wkv  + (size_t)l * D_ * 2 * D_;
        const float* bkv_l  = bkv  + (size_t)l * 2 * D_;
        const float* Wq_l   = Wq   + (size_t)l * D_ * D_;
        const float* bq_l   = bq   + (size_t)l * D_;
        const float* Wco_l  = Wco  + (size_t)l * D_ * D_;
        const float* bco_l  = bco  + (size_t)l * D_;
        const float* W1_l   = W1   + (size_t)l * D_ * F_;
        const float* b1_l   = b1   + (size_t)l * F_;
        const float* W2_l   = W2   + (size_t)l * F_ * D_;
        const float* b2_l   = b2   + (size_t)l * D_;

        // ---- self-attention block
        gemm_kernel<0><<<dim3(3 * D_ / 128, M_ / 128), 256, 0, stream>>>(
            y, Wqkv_l, bqkv_l, big, M_, 3 * D_, D_);
        fattn_kernel<<<dim3(T_ / 64, H_, B_), 512, 0, stream>>>(
            big, 3 * D_, 0, big, 3 * D_, D_, big, 3 * D_, 2 * D_, self_mask, abuf);
        gemm_kernel<0><<<dim3(D_ / 128, M_ / 128), 256, 0, stream>>>(
            abuf, Wo_l, bo_l, tmp, M_, D_, D_);
        ln_kernel<<<M_, 256, 0, stream>>>(tmp, y, g1 + l * D_, be1 + l * D_, y);

        // ---- cross-attention block (K,V from encoder output x)
        gemm_kernel<0><<<dim3(2 * D_ / 128, M_ / 128), 256, 0, stream>>>(
            x, Wkv_l, bkv_l, big, M_, 2 * D_, D_);
        gemm_kernel<0><<<dim3(D_ / 128, M_ / 128), 256, 0, stream>>>(
            y, Wq_l, bq_l, qb, M_, D_, D_);
        fattn_kernel<<<dim3(T_ / 64, H_, B_), 512, 0, stream>>>(
            qb, D_, 0, big, 2 * D_, 0, big, 2 * D_, D_, cross_mask, abuf);
        gemm_kernel<0><<<dim3(D_ / 128, M_ / 128), 256, 0, stream>>>(
            abuf, Wco_l, bco_l, tmp, M_, D_, D_);
        ln_kernel<<<M_, 256, 0, stream>>>(tmp, y, g2 + l * D_, be2 + l * D_, y);

        // ---- feed-forward block
        gemm_kernel<1><<<dim3(F_ / 128, M_ / 128), 256, 0, stream>>>(
            y, W1_l, b1_l, big, M_, F_, D_);
        gemm_kernel<0><<<dim3(D_ / 128, M_ / 128), 256, 0, stream>>>(
            big, W2_l, b2_l, tmp, M_, D_, F_);
        float* lnout = (l == L_ - 1) ? (float*)d_out : y;
        ln_kernel<<<M_, 256, 0, stream>>>(tmp, y, g3 + l * D_, be3 + l * D_, lnout);
    }
}

// Round 4
// 922.755 us; speedup vs baseline: 6.3644x; 2.0883x over previous
//
#include <hip/hip_runtime.h>
#include <math.h>

#define B_ 2
#define T_ 1024
#define D_ 512
#define H_ 8
#define HD_ 64
#define F_ 2048
#define L_ 2
#define V_ 32000
#define M_ (B_*T_)
#define EPS_ 1e-5f

typedef __attribute__((ext_vector_type(8))) short bf16x8;
typedef __attribute__((ext_vector_type(4))) float f32x4;
typedef unsigned short ushort_t;

__device__ inline ushort_t f2bf(float f) {   // round-to-nearest-even
    union { float f; unsigned u; } v; v.f = f;
    unsigned r = v.u + 0x7FFFu + ((v.u >> 16) & 1u);
    return (ushort_t)(r >> 16);
}

// ---------------------------------------------------------------------------
// Embedding + sinusoidal positional encoding -> fp32 y and bf16 ybf
// ---------------------------------------------------------------------------
__global__ __launch_bounds__(256) void embed_kernel(const int* __restrict__ tok,
                                                    const float* __restrict__ emb,
                                                    float* __restrict__ y,
                                                    ushort_t* __restrict__ ybf)
{
    int idx = blockIdx.x * 256 + threadIdx.x;      // over M_*D_
    int d   = idx & (D_ - 1);
    int row = idx >> 9;
    int t   = row & (T_ - 1);
    int token = tok[row];
    float arg = (float)t / powf(10000.f, (float)(d & ~1) / (float)D_);
    float pe  = (d & 1) ? cosf(arg) : sinf(arg);
    float v = emb[(size_t)token * D_ + d] + pe;
    y[idx] = v;
    ybf[idx] = f2bf(v);
}

// ---------------------------------------------------------------------------
// fp32 -> bf16 bulk convert (for x)
// ---------------------------------------------------------------------------
__global__ __launch_bounds__(256) void cvt_bf16_kernel(const float* __restrict__ in,
                                                       ushort_t* __restrict__ out)
{
    int i = (blockIdx.x * 256 + threadIdx.x) * 4;
    float4 v = *(const float4*)&in[i];
    ushort4 o;
    o.x = f2bf(v.x); o.y = f2bf(v.y); o.z = f2bf(v.z); o.w = f2bf(v.w);
    *(ushort4*)&out[i] = o;
}

// ---------------------------------------------------------------------------
// Weight transpose + convert: W[K][N] fp32 -> Wt[N][K] bf16. 64x64 tiles.
// ---------------------------------------------------------------------------
__global__ __launch_bounds__(256) void transpose_cvt_kernel(const float* __restrict__ W,
                                                            ushort_t* __restrict__ Wt,
                                                            int K, int N)
{
    __shared__ float tile[64][65];
    int k0 = blockIdx.y * 64, n0 = blockIdx.x * 64;
    int t = threadIdx.x;
    int r = t >> 4, c4 = (t & 15) * 4;
    #pragma unroll
    for (int p = 0; p < 4; ++p) {
        float4 v = *(const float4*)&W[(size_t)(k0 + p * 16 + r) * N + n0 + c4];
        tile[p * 16 + r][c4 + 0] = v.x; tile[p * 16 + r][c4 + 1] = v.y;
        tile[p * 16 + r][c4 + 2] = v.z; tile[p * 16 + r][c4 + 3] = v.w;
    }
    __syncthreads();
    #pragma unroll
    for (int p = 0; p < 4; ++p) {
        int n = p * 16 + r;
        ushort4 o;
        o.x = f2bf(tile[c4 + 0][n]); o.y = f2bf(tile[c4 + 1][n]);
        o.z = f2bf(tile[c4 + 2][n]); o.w = f2bf(tile[c4 + 3][n]);
        *(ushort4*)&Wt[(size_t)(n0 + n) * K + k0 + c4] = o;
    }
}

// ---------------------------------------------------------------------------
// bf16 MFMA GEMM: C[M,N] = A[M,K] @ Wt[N,K]^T + bias. 128x128 tile, BK=64,
// 256 thr = 4 waves (2x2), each wave 64x64 via 4x4 frags of 16x16x32 MFMA.
// LDS [row][64k] bf16, 16B-chunk XOR swizzle (pos ^= row&7): uniform banks.
// OUTMODE 0: fp32 out. OUTMODE 1: ReLU + bf16 out.
// ---------------------------------------------------------------------------
template<int OUTMODE>
__global__ __launch_bounds__(256) void gemm_bf16_kernel(
    const ushort_t* __restrict__ A,   // [M][K] bf16
    const ushort_t* __restrict__ Bt,  // [N][K] bf16
    const float* __restrict__ bias,   // [N]
    void* __restrict__ Cv, int M, int N, int K)
{
    __shared__ __attribute__((aligned(16))) ushort_t Al[128 * 64];
    __shared__ __attribute__((aligned(16))) ushort_t Bl[128 * 64];
    int tid = threadIdx.x;
    int w = tid >> 6, l = tid & 63;
    int wr = w >> 1, wc = w & 1;
    int brow = blockIdx.y * 128, bcol = blockIdx.x * 128;

    f32x4 acc[4][4];
    #pragma unroll
    for (int m = 0; m < 4; ++m)
        #pragma unroll
        for (int n = 0; n < 4; ++n)
            acc[m][n] = (f32x4){0.f, 0.f, 0.f, 0.f};

    for (int kt = 0; kt < K; kt += 64) {
        __syncthreads();   // previous tile fully consumed
        // ---- stage A,B tiles: 1024 16B-chunks each, 4 per thread
        #pragma unroll
        for (int i = 0; i < 4; ++i) {
            int c = tid + i * 256;
            int row = c >> 3, pos = c & 7;
            int sp = pos ^ (row & 7);     // swizzled source chunk
            uint4 va = *(const uint4*)&A[(size_t)(brow + row) * K + kt + sp * 8];
            *(uint4*)&Al[row * 64 + pos * 8] = va;
            uint4 vb = *(const uint4*)&Bt[(size_t)(bcol + row) * K + kt + sp * 8];
            *(uint4*)&Bl[row * 64 + pos * 8] = vb;
        }
        __syncthreads();   // tiles ready

        #pragma unroll
        for (int kk = 0; kk < 2; ++kk) {
            bf16x8 af[4], bfr[4];
            int cbase = kk * 4 + (l >> 4);
            #pragma unroll
            for (int m = 0; m < 4; ++m) {
                int row = wr * 64 + m * 16 + (l & 15);
                af[m] = *(const bf16x8*)&Al[row * 64 + (cbase ^ (row & 7)) * 8];
            }
            #pragma unroll
            for (int n = 0; n < 4; ++n) {
                int row = wc * 64 + n * 16 + (l & 15);
                bfr[n] = *(const bf16x8*)&Bl[row * 64 + (cbase ^ (row & 7)) * 8];
            }
            #pragma unroll
            for (int m = 0; m < 4; ++m)
                #pragma unroll
                for (int n = 0; n < 4; ++n)
                    acc[m][n] = __builtin_amdgcn_mfma_f32_16x16x32_bf16(
                        af[m], bfr[n], acc[m][n], 0, 0, 0);
        }
    }

    // ---- epilogue: D row=(l>>4)*4+r, col=l&15 within each 16x16 frag
    int colb = bcol + wc * 64;
    #pragma unroll
    for (int n = 0; n < 4; ++n) {
        int col = colb + n * 16 + (l & 15);
        float bv = bias[col];
        #pragma unroll
        for (int m = 0; m < 4; ++m) {
            int rowb = brow + wr * 64 + m * 16 + (l >> 4) * 4;
            #pragma unroll
            for (int r = 0; r < 4; ++r) {
                float v = acc[m][n][r] + bv;
                if (OUTMODE == 1) {
                    v = fmaxf(v, 0.f);
                    ((ushort_t*)Cv)[(size_t)(rowb + r) * N + col] = f2bf(v);
                } else {
                    ((float*)Cv)[(size_t)(rowb + r) * N + col] = v;
                }
            }
        }
    }
}

// ---------------------------------------------------------------------------
// Flash attention (fp32 VALU), unchanged math; output now bf16.
// Block = 512 thr, 64-q-row tile per (b,h). LDS XOR-swizzled.
// ---------------------------------------------------------------------------
__global__ __launch_bounds__(512) void fattn_kernel(
    const float* __restrict__ Q, int qld, int qoff,
    const float* __restrict__ Kb, int kld, int koff,
    const float* __restrict__ Vb, int vld, int voff,
    const float* __restrict__ mask, ushort_t* __restrict__ out)
{
    __shared__ float Qs[HD_][64];
    __shared__ float Ks[HD_][64];
    __shared__ float Vs[64][HD_];

    const int tid = threadIdx.x;
    const int tx = tid & 15, ty = tid >> 4;
    const int qbase = blockIdx.x * 64;
    const int h = blockIdx.y, b = blockIdx.z;
    const int hoff = h * HD_;

    #pragma unroll
    for (int l = 0; l < 2; ++l) {
        int id = tid + l * 512;
        int qr = id >> 4, dq = id & 15;
        float4 v = *(const float4*)&Q[(size_t)(b * T_ + qbase + qr) * qld + qoff + hoff + 4 * dq];
        { int d = 4 * dq;     Qs[d][qr ^ ((d & 7) << 2)] = v.x; }
        { int d = 4 * dq + 1; Qs[d][qr ^ ((d & 7) << 2)] = v.y; }
        { int d = 4 * dq + 2; Qs[d][qr ^ ((d & 7) << 2)] = v.z; }
        { int d = 4 * dq + 3; Qs[d][qr ^ ((d & 7) << 2)] = v.w; }
    }

    float m0 = -1e30f, m1 = -1e30f, l0 = 0.f, l1 = 0.f;
    float o0[4] = {0.f, 0.f, 0.f, 0.f}, o1[4] = {0.f, 0.f, 0.f, 0.f};

    for (int kt = 0; kt < T_ / 64; ++kt) {
        const int k0 = kt * 64;
        __syncthreads();

        #pragma unroll
        for (int l = 0; l < 2; ++l) {
            int id = tid + l * 512;
            int kr = id >> 4, dq = id & 15;
            float4 kv = *(const float4*)&Kb[(size_t)(b * T_ + k0 + kr) * kld + koff + hoff + 4 * dq];
            float4 vv = *(const float4*)&Vb[(size_t)(b * T_ + k0 + kr) * vld + voff + hoff + 4 * dq];
            { int d = 4 * dq;     Ks[d][kr ^ ((d & 7) << 2)] = kv.x; }
            { int d = 4 * dq + 1; Ks[d][kr ^ ((d & 7) << 2)] = kv.y; }
            { int d = 4 * dq + 2; Ks[d][kr ^ ((d & 7) << 2)] = kv.z; }
            { int d = 4 * dq + 3; Ks[d][kr ^ ((d & 7) << 2)] = kv.w; }
            *(float4*)&Vs[kr][(4 * dq) ^ ((kr & 7) << 2)] = vv;
        }
        const size_t mbase = (size_t)b * T_ * T_ + (size_t)(qbase + 2 * ty) * T_ + k0 + 4 * tx;
        float4 mk0 = *(const float4*)&mask[mbase];
        float4 mk1 = *(const float4*)&mask[mbase + T_];
        __syncthreads();

        float s0[4] = {0.f, 0.f, 0.f, 0.f}, s1[4] = {0.f, 0.f, 0.f, 0.f};
        #pragma unroll 8
        for (int d = 0; d < HD_; ++d) {
            int sw = (d & 7) << 2;
            float2 a = *(const float2*)&Qs[d][(2 * ty) ^ sw];
            float4 bb = *(const float4*)&Ks[d][(4 * tx) ^ sw];
            s0[0] = fmaf(a.x, bb.x, s0[0]); s0[1] = fmaf(a.x, bb.y, s0[1]);
            s0[2] = fmaf(a.x, bb.z, s0[2]); s0[3] = fmaf(a.x, bb.w, s0[3]);
            s1[0] = fmaf(a.y, bb.x, s1[0]); s1[1] = fmaf(a.y, bb.y, s1[1]);
            s1[2] = fmaf(a.y, bb.z, s1[2]); s1[3] = fmaf(a.y, bb.w, s1[3]);
        }
        s0[0] = fmaf(s0[0], 0.125f, mk0.x); s0[1] = fmaf(s0[1], 0.125f, mk0.y);
        s0[2] = fmaf(s0[2], 0.125f, mk0.z); s0[3] = fmaf(s0[3], 0.125f, mk0.w);
        s1[0] = fmaf(s1[0], 0.125f, mk1.x); s1[1] = fmaf(s1[1], 0.125f, mk1.y);
        s1[2] = fmaf(s1[2], 0.125f, mk1.z); s1[3] = fmaf(s1[3], 0.125f, mk1.w);

        {
            float pm = fmaxf(fmaxf(s0[0], s0[1]), fmaxf(s0[2], s0[3]));
            pm = fmaxf(pm, __shfl_xor(pm, 1)); pm = fmaxf(pm, __shfl_xor(pm, 2));
            pm = fmaxf(pm, __shfl_xor(pm, 4)); pm = fmaxf(pm, __shfl_xor(pm, 8));
            float mn = fmaxf(m0, pm);
            float sc = __expf(m0 - mn);
            float rs = 0.f;
            s0[0] = __expf(s0[0] - mn); rs += s0[0];
            s0[1] = __expf(s0[1] - mn); rs += s0[1];
            s0[2] = __expf(s0[2] - mn); rs += s0[2];
            s0[3] = __expf(s0[3] - mn); rs += s0[3];
            rs += __shfl_xor(rs, 1); rs += __shfl_xor(rs, 2);
            rs += __shfl_xor(rs, 4); rs += __shfl_xor(rs, 8);
            l0 = l0 * sc + rs; m0 = mn;
            o0[0] *= sc; o0[1] *= sc; o0[2] *= sc; o0[3] *= sc;
        }
        {
            float pm = fmaxf(fmaxf(s1[0], s1[1]), fmaxf(s1[2], s1[3]));
            pm = fmaxf(pm, __shfl_xor(pm, 1)); pm = fmaxf(pm, __shfl_xor(pm, 2));
            pm = fmaxf(pm, __shfl_xor(pm, 4)); pm = fmaxf(pm, __shfl_xor(pm, 8));
            float mn = fmaxf(m1, pm);
            float sc = __expf(m1 - mn);
            float rs = 0.f;
            s1[0] = __expf(s1[0] - mn); rs += s1[0];
            s1[1] = __expf(s1[1] - mn); rs += s1[1];
            s1[2] = __expf(s1[2] - mn); rs += s1[2];
            s1[3] = __expf(s1[3] - mn); rs += s1[3];
            rs += __shfl_xor(rs, 1); rs += __shfl_xor(rs, 2);
            rs += __shfl_xor(rs, 4); rs += __shfl_xor(rs, 8);
            l1 = l1 * sc + rs; m1 = mn;
            o1[0] *= sc; o1[1] *= sc; o1[2] *= sc; o1[3] *= sc;
        }

        #pragma unroll 4
        for (int kq = 0; kq < 16; ++kq) {
            int src = (tid & 48) | kq;
            #pragma unroll
            for (int j = 0; j < 4; ++j) {
                float p0 = __shfl(s0[j], src, 64);
                float p1 = __shfl(s1[j], src, 64);
                int k = 4 * kq + j;
                int sw = (k & 7) << 2;
                float4 vv = *(const float4*)&Vs[k][(4 * tx) ^ sw];
                o0[0] = fmaf(p0, vv.x, o0[0]); o0[1] = fmaf(p0, vv.y, o0[1]);
                o0[2] = fmaf(p0, vv.z, o0[2]); o0[3] = fmaf(p0, vv.w, o0[3]);
                o1[0] = fmaf(p1, vv.x, o1[0]); o1[1] = fmaf(p1, vv.y, o1[1]);
                o1[2] = fmaf(p1, vv.z, o1[2]); o1[3] = fmaf(p1, vv.w, o1[3]);
            }
        }
    }

    float inv0 = 1.f / l0, inv1 = 1.f / l1;
    ushort4 r0p, r1p;
    r0p.x = f2bf(o0[0] * inv0); r0p.y = f2bf(o0[1] * inv0);
    r0p.z = f2bf(o0[2] * inv0); r0p.w = f2bf(o0[3] * inv0);
    r1p.x = f2bf(o1[0] * inv1); r1p.y = f2bf(o1[1] * inv1);
    r1p.z = f2bf(o1[2] * inv1); r1p.w = f2bf(o1[3] * inv1);
    size_t obase = (size_t)(b * T_ + qbase + 2 * ty) * D_ + hoff + 4 * tx;
    *(ushort4*)&out[obase]      = r0p;
    *(ushort4*)&out[obase + D_] = r1p;
}

// ---------------------------------------------------------------------------
// Fused residual-add + LayerNorm -> fp32 out (+ optional bf16 copy)
// ---------------------------------------------------------------------------
__global__ __launch_bounds__(256) void ln_kernel(const float* __restrict__ a,
                                                 const float* __restrict__ r,
                                                 const float* __restrict__ g,
                                                 const float* __restrict__ be,
                                                 float* __restrict__ out,
                                                 ushort_t* __restrict__ outbf)
{
    __shared__ float red[256], red2[256];
    int row = blockIdx.x;
    int tid = threadIdx.x;
    size_t base = (size_t)row * D_;
    float v0 = a[base + tid]       + r[base + tid];
    float v1 = a[base + tid + 256] + r[base + tid + 256];
    red[tid] = v0 + v1;
    red2[tid] = v0 * v0 + v1 * v1;
    __syncthreads();
    for (int st = 128; st > 0; st >>= 1) {
        if (tid < st) { red[tid] += red[tid + st]; red2[tid] += red2[tid + st]; }
        __syncthreads();
    }
    float mean = red[0] * (1.f / D_);
    float var  = red2[0] * (1.f / D_) - mean * mean;
    float rstd = rsqrtf(var + EPS_);
    float w0 = (v0 - mean) * rstd * g[tid]       + be[tid];
    float w1 = (v1 - mean) * rstd * g[tid + 256] + be[tid + 256];
    out[base + tid]       = w0;
    out[base + tid + 256] = w1;
    if (outbf) {
        outbf[base + tid]       = f2bf(w0);
        outbf[base + tid + 256] = f2bf(w1);
    }
}

// ---------------------------------------------------------------------------
// Workspace (float units, total 6M floats = 24 MB):
//   y    ws+0    [M,D] fp32 residual stream
//   big  ws+1M   3M-float shared region:
//        self: qkv fp32 [M,3D] -> (dead) tmpA = big[0..1M)
//        cross: kv fp32 [M,2D] + qb [M,D] at big+2M -> tmpA
//        ffn:  hbf bf16 [M,F] in big[0..1M floats) ; tmpB = big+1M
//   WtS  ws+4M   transposed bf16 weight slot (max 1M bf16 = 0.5M floats)
//   ybf  ws+4.5M bf16 copy of y
//   xbf  ws+5M   bf16 copy of x
//   abf  ws+5.5M bf16 attention output
// ---------------------------------------------------------------------------
extern "C" void kernel_launch(void* const* d_in, const int* in_sizes, int n_in,
                              void* d_out, int out_size, void* d_ws, size_t ws_size,
                              hipStream_t stream)
{
    const float* x          = (const float*)d_in[0];
    const int*   y_tokens   = (const int*)  d_in[1];
    const float* self_mask  = (const float*)d_in[2];
    const float* cross_mask = (const float*)d_in[3];
    const float* emb        = (const float*)d_in[4];
    const float* Wqkv = (const float*)d_in[5];  const float* bqkv = (const float*)d_in[6];
    const float* Wo   = (const float*)d_in[7];  const float* bo   = (const float*)d_in[8];
    const float* Wkv  = (const float*)d_in[9];  const float* bkv  = (const float*)d_in[10];
    const float* Wq   = (const float*)d_in[11]; const float* bq   = (const float*)d_in[12];
    const float* Wco  = (const float*)d_in[13]; const float* bco  = (const float*)d_in[14];
    const float* W1   = (const float*)d_in[15]; const float* b1   = (const float*)d_in[16];
    const float* W2   = (const float*)d_in[17]; const float* b2   = (const float*)d_in[18];
    const float* g1   = (const float*)d_in[19]; const float* be1  = (const float*)d_in[20];
    const float* g2   = (const float*)d_in[21]; const float* be2  = (const float*)d_in[22];
    const float* g3   = (const float*)d_in[23]; const float* be3  = (const float*)d_in[24];

    float* ws = (float*)d_ws;
    const size_t MD = (size_t)M_ * D_;            // 1M floats
    float*    y    = ws;
    float*    big  = ws + MD;
    ushort_t* WtS  = (ushort_t*)(ws + 4 * MD);
    ushort_t* ybf  = (ushort_t*)(ws + 4 * MD + MD / 2);
    ushort_t* xbf  = (ushort_t*)(ws + 5 * MD);
    ushort_t* abf  = (ushort_t*)(ws + 5 * MD + MD / 2);

    float*    tmpA = big;                         // self/cross pre-LN
    float*    qb   = big + 2 * MD;                // cross-attn Q fp32
    ushort_t* hbf  = (ushort_t*)big;              // ffn hidden bf16 [M,F]
    float*    tmpB = big + MD;                    // ffn pre-LN

    embed_kernel<<<(M_ * D_) / 256, 256, 0, stream>>>(y_tokens, emb, y, ybf);
    cvt_bf16_kernel<<<(M_ * D_) / 1024, 256, 0, stream>>>(x, xbf);

    for (int l = 0; l < L_; ++l) {
        const float* Wqkv_l = Wqkv + (size_t)l * D_ * 3 * D_;
        const float* bqkv_l = bqkv + (size_t)l * 3 * D_;
        const float* Wo_l   = Wo   + (size_t)l * D_ * D_;
        const float* bo_l   = bo   + (size_t)l * D_;
        const float* Wkv_l  = Wkv  + (size_t)l * D_ * 2 * D_;
        const float* bkv_l  = bkv  + (size_t)l * 2 * D_;
        const float* Wq_l   = Wq   + (size_t)l * D_ * D_;
        const float* bq_l   = bq   + (size_t)l * D_;
        const float* Wco_l  = Wco  + (size_t)l * D_ * D_;
        const float* bco_l  = bco  + (size_t)l * D_;
        const float* W1_l   = W1   + (size_t)l * D_ * F_;
        const float* b1_l   = b1   + (size_t)l * F_;
        const float* W2_l   = W2   + (size_t)l * F_ * D_;
        const float* b2_l   = b2   + (size_t)l * D_;

        // ---- self-attention block
        transpose_cvt_kernel<<<dim3(3 * D_ / 64, D_ / 64), 256, 0, stream>>>(
            Wqkv_l, WtS, D_, 3 * D_);
        gemm_bf16_kernel<0><<<dim3(3 * D_ / 128, M_ / 128), 256, 0, stream>>>(
            ybf, WtS, bqkv_l, big, M_, 3 * D_, D_);
        fattn_kernel<<<dim3(T_ / 64, H_, B_), 512, 0, stream>>>(
            big, 3 * D_, 0, big, 3 * D_, D_, big, 3 * D_, 2 * D_, self_mask, abf);
        transpose_cvt_kernel<<<dim3(D_ / 64, D_ / 64), 256, 0, stream>>>(
            Wo_l, WtS, D_, D_);
        gemm_bf16_kernel<0><<<dim3(D_ / 128, M_ / 128), 256, 0, stream>>>(
            abf, WtS, bo_l, tmpA, M_, D_, D_);
        ln_kernel<<<M_, 256, 0, stream>>>(tmpA, y, g1 + l * D_, be1 + l * D_, y, ybf);

        // ---- cross-attention block
        transpose_cvt_kernel<<<dim3(2 * D_ / 64, D_ / 64), 256, 0, stream>>>(
            Wkv_l, WtS, D_, 2 * D_);
        gemm_bf16_kernel<0><<<dim3(2 * D_ / 128, M_ / 128), 256, 0, stream>>>(
            xbf, WtS, bkv_l, big, M_, 2 * D_, D_);
        transpose_cvt_kernel<<<dim3(D_ / 64, D_ / 64), 256, 0, stream>>>(
            Wq_l, WtS, D_, D_);
        gemm_bf16_kernel<0><<<dim3(D_ / 128, M_ / 128), 256, 0, stream>>>(
            ybf, WtS, bq_l, qb, M_, D_, D_);
        fattn_kernel<<<dim3(T_ / 64, H_, B_), 512, 0, stream>>>(
            qb, D_, 0, big, 2 * D_, 0, big, 2 * D_, D_, cross_mask, abf);
        transpose_cvt_kernel<<<dim3(D_ / 64, D_ / 64), 256, 0, stream>>>(
            Wco_l, WtS, D_, D_);
        gemm_bf16_kernel<0><<<dim3(D_ / 128, M_ / 128), 256, 0, stream>>>(
            abf, WtS, bco_l, tmpA, M_, D_, D_);
        ln_kernel<<<M_, 256, 0, stream>>>(tmpA, y, g2 + l * D_, be2 + l * D_, y, ybf);

        // ---- feed-forward block
        transpose_cvt_kernel<<<dim3(F_ / 64, D_ / 64), 256, 0, stream>>>(
            W1_l, WtS, D_, F_);
        gemm_bf16_kernel<1><<<dim3(F_ / 128, M_ / 128), 256, 0, stream>>>(
            ybf, WtS, b1_l, hbf, M_, F_, D_);
        transpose_cvt_kernel<<<dim3(D_ / 64, F_ / 64), 256, 0, stream>>>(
            W2_l, WtS, F_, D_);
        gemm_bf16_kernel<0><<<dim3(D_ / 128, M_ / 128), 256, 0, stream>>>(
            hbf, WtS, b2_l, tmpB, M_, D_, F_);
        float* lnout = (l == L_ - 1) ? (float*)d_out : y;
        ln_kernel<<<M_, 256, 0, stream>>>(tmpB, y, g3 + l * D_, be3 + l * D_, lnout, ybf);
    }
}

// Round 14
// 618.733 us; speedup vs baseline: 9.4917x; 1.4914x over previous
//
#include <hip/hip_runtime.h>
#include <math.h>

#define B_ 2
#define T_ 1024
#define D_ 512
#define H_ 8
#define HD_ 64
#define F_ 2048
#define L_ 2
#define V_ 32000
#define M_ (B_*T_)
#define EPS_ 1e-5f

typedef __attribute__((ext_vector_type(8))) short bf16x8;
typedef __attribute__((ext_vector_type(4))) float f32x4;
typedef unsigned short ushort_t;

__device__ inline ushort_t f2bf(float f) {   // round-to-nearest-even
    union { float f; unsigned u; } v; v.f = f;
    unsigned r = v.u + 0x7FFFu + ((v.u >> 16) & 1u);
    return (ushort_t)(r >> 16);
}

// ---------------------------------------------------------------------------
// Embedding + sinusoidal positional encoding -> fp32 y and bf16 ybf
// ---------------------------------------------------------------------------
__global__ __launch_bounds__(256) void embed_kernel(const int* __restrict__ tok,
                                                    const float* __restrict__ emb,
                                                    float* __restrict__ y,
                                                    ushort_t* __restrict__ ybf)
{
    int idx = blockIdx.x * 256 + threadIdx.x;      // over M_*D_
    int d   = idx & (D_ - 1);
    int row = idx >> 9;
    int t   = row & (T_ - 1);
    int token = tok[row];
    float arg = (float)t / powf(10000.f, (float)(d & ~1) / (float)D_);
    float pe  = (d & 1) ? cosf(arg) : sinf(arg);
    float v = emb[(size_t)token * D_ + d] + pe;
    y[idx] = v;
    ybf[idx] = f2bf(v);
}

__global__ __launch_bounds__(256) void cvt_bf16_kernel(const float* __restrict__ in,
                                                       ushort_t* __restrict__ out)
{
    int i = (blockIdx.x * 256 + threadIdx.x) * 4;
    float4 v = *(const float4*)&in[i];
    ushort4 o;
    o.x = f2bf(v.x); o.y = f2bf(v.y); o.z = f2bf(v.z); o.w = f2bf(v.w);
    *(ushort4*)&out[i] = o;
}

// ---------------------------------------------------------------------------
// Weight transpose + convert: W[K][N] fp32 -> Wt[N][K] bf16. 64x64 tiles.
// ---------------------------------------------------------------------------
__global__ __launch_bounds__(256) void transpose_cvt_kernel(const float* __restrict__ W,
                                                            ushort_t* __restrict__ Wt,
                                                            int K, int N)
{
    __shared__ float tile[64][65];
    int k0 = blockIdx.y * 64, n0 = blockIdx.x * 64;
    int t = threadIdx.x;
    int r = t >> 4, c4 = (t & 15) * 4;
    #pragma unroll
    for (int p = 0; p < 4; ++p) {
        float4 v = *(const float4*)&W[(size_t)(k0 + p * 16 + r) * N + n0 + c4];
        tile[p * 16 + r][c4 + 0] = v.x; tile[p * 16 + r][c4 + 1] = v.y;
        tile[p * 16 + r][c4 + 2] = v.z; tile[p * 16 + r][c4 + 3] = v.w;
    }
    __syncthreads();
    #pragma unroll
    for (int p = 0; p < 4; ++p) {
        int n = p * 16 + r;
        ushort4 o;
        o.x = f2bf(tile[c4 + 0][n]); o.y = f2bf(tile[c4 + 1][n]);
        o.z = f2bf(tile[c4 + 2][n]); o.w = f2bf(tile[c4 + 3][n]);
        *(ushort4*)&Wt[(size_t)(n0 + n) * K + k0 + c4] = o;
    }
}

// ---------------------------------------------------------------------------
// bf16 MFMA GEMM: C[M,N] = A[M,K] @ Wt[N,K]^T + bias. 128x128 tile, BK=64.
// OUTMODE 0: fp32 out. 1: ReLU+bf16. 2: bf16.
// ---------------------------------------------------------------------------
template<int OUTMODE>
__global__ __launch_bounds__(256) void gemm_bf16_kernel(
    const ushort_t* __restrict__ A,   // [M][K] bf16
    const ushort_t* __restrict__ Bt,  // [N][K] bf16
    const float* __restrict__ bias,   // [N]
    void* __restrict__ Cv, int M, int N, int K)
{
    __shared__ __attribute__((aligned(16))) ushort_t Al[128 * 64];
    __shared__ __attribute__((aligned(16))) ushort_t Bl[128 * 64];
    int tid = threadIdx.x;
    int w = tid >> 6, l = tid & 63;
    int wr = w >> 1, wc = w & 1;
    int brow = blockIdx.y * 128, bcol = blockIdx.x * 128;

    f32x4 acc[4][4];
    #pragma unroll
    for (int m = 0; m < 4; ++m)
        #pragma unroll
        for (int n = 0; n < 4; ++n)
            acc[m][n] = (f32x4){0.f, 0.f, 0.f, 0.f};

    for (int kt = 0; kt < K; kt += 64) {
        __syncthreads();
        #pragma unroll
        for (int i = 0; i < 4; ++i) {
            int c = tid + i * 256;
            int row = c >> 3, pos = c & 7;
            int sp = pos ^ (row & 7);
            uint4 va = *(const uint4*)&A[(size_t)(brow + row) * K + kt + sp * 8];
            *(uint4*)&Al[row * 64 + pos * 8] = va;
            uint4 vb = *(const uint4*)&Bt[(size_t)(bcol + row) * K + kt + sp * 8];
            *(uint4*)&Bl[row * 64 + pos * 8] = vb;
        }
        __syncthreads();

        #pragma unroll
        for (int kk = 0; kk < 2; ++kk) {
            bf16x8 af[4], bfr[4];
            int cbase = kk * 4 + (l >> 4);
            #pragma unroll
            for (int m = 0; m < 4; ++m) {
                int row = wr * 64 + m * 16 + (l & 15);
                af[m] = *(const bf16x8*)&Al[row * 64 + (cbase ^ (row & 7)) * 8];
            }
            #pragma unroll
            for (int n = 0; n < 4; ++n) {
                int row = wc * 64 + n * 16 + (l & 15);
                bfr[n] = *(const bf16x8*)&Bl[row * 64 + (cbase ^ (row & 7)) * 8];
            }
            #pragma unroll
            for (int m = 0; m < 4; ++m)
                #pragma unroll
                for (int n = 0; n < 4; ++n)
                    acc[m][n] = __builtin_amdgcn_mfma_f32_16x16x32_bf16(
                        af[m], bfr[n], acc[m][n], 0, 0, 0);
        }
    }

    int colb = bcol + wc * 64;
    #pragma unroll
    for (int n = 0; n < 4; ++n) {
        int col = colb + n * 16 + (l & 15);
        float bv = bias[col];
        #pragma unroll
        for (int m = 0; m < 4; ++m) {
            int rowb = brow + wr * 64 + m * 16 + (l >> 4) * 4;
            #pragma unroll
            for (int r = 0; r < 4; ++r) {
                float v = acc[m][n][r] + bv;
                if (OUTMODE == 1) {
                    v = fmaxf(v, 0.f);
                    ((ushort_t*)Cv)[(size_t)(rowb + r) * N + col] = f2bf(v);
                } else if (OUTMODE == 2) {
                    ((ushort_t*)Cv)[(size_t)(rowb + r) * N + col] = f2bf(v);
                } else {
                    ((float*)Cv)[(size_t)(rowb + r) * N + col] = v;
                }
            }
        }
    }
}

// ---------------------------------------------------------------------------
// MFMA flash attention (bf16 in, fp32 softmax, bf16 out).
// Block = 256 thr = 4 waves; wave w owns q-rows [qt*64+16w, +16) of head h.
// Swapped QK^T: S^T = K·Q^T  (lane q = l&15, keys spread over n,r,g).
// PV: O^T = V^T·P^T with V staged transposed in LDS, P^T redistributed
// in-register via cvt_pk_bf16 + 8 shfls per K-half.
// Grid (H, T/64, B): head fastest => blocks sharing a mask tile co-schedule.
// ---------------------------------------------------------------------------
__global__ __launch_bounds__(256) void fattn_mfma_kernel(
    const ushort_t* __restrict__ Qg, int qld, int qoff,
    const ushort_t* __restrict__ Kg, int kld, int koff,
    const ushort_t* __restrict__ Vg, int vld, int voff,
    const float* __restrict__ mask, ushort_t* __restrict__ out)
{
    __shared__ __attribute__((aligned(16))) ushort_t Kl[64 * 64];  // [key][d] swz
    __shared__ __attribute__((aligned(16))) ushort_t Vt[64 * 64];  // [d][key] swz

    const int tid = threadIdx.x;
    const int l = tid & 63, w = tid >> 6;
    const int q16 = l & 15, g = l >> 4, g2 = g >> 1;
    const int h = blockIdx.x, qt = blockIdx.y, b = blockIdx.z;
    const int hoff = h * HD_;
    const int qrow = qt * 64 + w * 16 + q16;           // within T_

    // Q^T B-fragments: lane holds Q[qrow][kk*32 + g*8 .. +8]
    const size_t qgbase = (size_t)(b * T_ + qrow) * qld + qoff + hoff;
    bf16x8 qf0 = *(const bf16x8*)&Qg[qgbase + g * 8];
    bf16x8 qf1 = *(const bf16x8*)&Qg[qgbase + 32 + g * 8];

    f32x4 oacc[4];                                     // O^T: d=nd*16+g*4+r, q=q16
    #pragma unroll
    for (int nd = 0; nd < 4; ++nd) oacc[nd] = (f32x4){0.f, 0.f, 0.f, 0.f};
    float mrow = -1e30f, lrow = 0.f;

    for (int kt = 0; kt < T_ / 64; ++kt) {
        const int k0 = kt * 64;
        __syncthreads();   // previous tile consumed

        // ---- stage K row-major (16B chunks, source-side XOR swizzle)
        #pragma unroll
        for (int i = 0; i < 2; ++i) {
            int c = tid + i * 256;
            int row = c >> 3, pos = c & 7;
            int sp = pos ^ (row & 7);
            uint4 kv = *(const uint4*)&Kg[(size_t)(b * T_ + k0 + row) * kld + koff + hoff + sp * 8];
            *(uint4*)&Kl[row * 64 + pos * 8] = kv;
        }
        // ---- stage V transposed: Vt[d][key], packed b32 (2 keys), XOR swizzle
        {
            int kp = tid & 31, dc = tid >> 5;          // key-pair, d-chunk
            const ushort_t* vp = &Vg[(size_t)(b * T_ + k0 + 2 * kp) * vld + voff + hoff + dc * 8];
            uint4 a0 = *(const uint4*)vp;
            uint4 a1 = *(const uint4*)(vp + vld);
            const ushort_t* va = (const ushort_t*)&a0;
            const ushort_t* vb = (const ushort_t*)&a1;
            #pragma unroll
            for (int j = 0; j < 8; ++j) {
                unsigned pw = (unsigned)va[j] | ((unsigned)vb[j] << 16);
                *(unsigned*)((char*)Vt + (dc * 8 + j) * 128 + (((kp >> 2) ^ j) << 4) + ((kp & 3) << 2)) = pw;
            }
        }
        // ---- mask tile (float4 per key-subtile n): keys n*16+g*4+{0..3}
        const size_t mbase = (size_t)b * T_ * T_ + (size_t)qrow * T_ + k0 + g * 4;
        float4 mk0 = *(const float4*)&mask[mbase];
        float4 mk1 = *(const float4*)&mask[mbase + 16];
        float4 mk2 = *(const float4*)&mask[mbase + 32];
        float4 mk3 = *(const float4*)&mask[mbase + 48];
        __syncthreads();   // tiles ready

        // ---- S^T = K·Q^T : acc_s[n][r]: key = n*16+g*4+r, q = q16
        f32x4 sacc[4];
        #pragma unroll
        for (int n = 0; n < 4; ++n) sacc[n] = (f32x4){0.f, 0.f, 0.f, 0.f};
        #pragma unroll
        for (int kk = 0; kk < 2; ++kk) {
            bf16x8 qf = kk ? qf1 : qf0;
            #pragma unroll
            for (int n = 0; n < 4; ++n) {
                int row = n * 16 + q16;                // key row in Kl
                bf16x8 ak = *(const bf16x8*)&Kl[row * 64 + ((kk * 4 + g) ^ (row & 7)) * 8];
                sacc[n] = __builtin_amdgcn_mfma_f32_16x16x32_bf16(ak, qf, sacc[n], 0, 0, 0);
            }
        }

        // ---- scale + mask + online softmax (lane-local row q16)
        float p[4][4];
        p[0][0] = fmaf(sacc[0][0], 0.125f, mk0.x); p[0][1] = fmaf(sacc[0][1], 0.125f, mk0.y);
        p[0][2] = fmaf(sacc[0][2], 0.125f, mk0.z); p[0][3] = fmaf(sacc[0][3], 0.125f, mk0.w);
        p[1][0] = fmaf(sacc[1][0], 0.125f, mk1.x); p[1][1] = fmaf(sacc[1][1], 0.125f, mk1.y);
        p[1][2] = fmaf(sacc[1][2], 0.125f, mk1.z); p[1][3] = fmaf(sacc[1][3], 0.125f, mk1.w);
        p[2][0] = fmaf(sacc[2][0], 0.125f, mk2.x); p[2][1] = fmaf(sacc[2][1], 0.125f, mk2.y);
        p[2][2] = fmaf(sacc[2][2], 0.125f, mk2.z); p[2][3] = fmaf(sacc[2][3], 0.125f, mk2.w);
        p[3][0] = fmaf(sacc[3][0], 0.125f, mk3.x); p[3][1] = fmaf(sacc[3][1], 0.125f, mk3.y);
        p[3][2] = fmaf(sacc[3][2], 0.125f, mk3.z); p[3][3] = fmaf(sacc[3][3], 0.125f, mk3.w);

        float tmax = -1e30f;
        #pragma unroll
        for (int n = 0; n < 4; ++n)
            #pragma unroll
            for (int r = 0; r < 4; ++r) tmax = fmaxf(tmax, p[n][r]);
        tmax = fmaxf(tmax, __shfl_xor(tmax, 16, 64));
        tmax = fmaxf(tmax, __shfl_xor(tmax, 32, 64));
        float mn = fmaxf(mrow, tmax);
        float sc = __expf(mrow - mn);
        float rs = 0.f;
        #pragma unroll
        for (int n = 0; n < 4; ++n)
            #pragma unroll
            for (int r = 0; r < 4; ++r) { p[n][r] = __expf(p[n][r] - mn); rs += p[n][r]; }
        rs += __shfl_xor(rs, 16, 64);
        rs += __shfl_xor(rs, 32, 64);
        lrow = lrow * sc + rs; mrow = mn;
        #pragma unroll
        for (int nd = 0; nd < 4; ++nd) {
            oacc[nd][0] *= sc; oacc[nd][1] *= sc; oacc[nd][2] *= sc; oacc[nd][3] *= sc;
        }

        // ---- pack P -> bf16 pairs (lo = even r)
        unsigned plo[4], phi[4];
        #pragma unroll
        for (int n = 0; n < 4; ++n) {
            asm("v_cvt_pk_bf16_f32 %0, %1, %2" : "=v"(plo[n]) : "v"(p[n][0]), "v"(p[n][1]));
            asm("v_cvt_pk_bf16_f32 %0, %1, %2" : "=v"(phi[n]) : "v"(p[n][2]), "v"(p[n][3]));
        }

        // ---- PV: O^T += V^T·P^T  (B-frag built by shfl redistribution)
        const int srcA = ((g & 1) << 5) + q16;
        const int srcB = srcA + 16;
        #pragma unroll
        for (int kk = 0; kk < 2; ++kk) {
            unsigned a0 = __shfl((int)plo[2 * kk],     srcA, 64);
            unsigned a1 = __shfl((int)phi[2 * kk],     srcA, 64);
            unsigned a2 = __shfl((int)plo[2 * kk],     srcB, 64);
            unsigned a3 = __shfl((int)phi[2 * kk],     srcB, 64);
            unsigned b0 = __shfl((int)plo[2 * kk + 1], srcA, 64);
            unsigned b1 = __shfl((int)phi[2 * kk + 1], srcA, 64);
            unsigned b2 = __shfl((int)plo[2 * kk + 1], srcB, 64);
            unsigned b3 = __shfl((int)phi[2 * kk + 1], srcB, 64);
            union { unsigned u[4]; bf16x8 v; } pb;
            pb.u[0] = g2 ? b0 : a0; pb.u[1] = g2 ? b1 : a1;
            pb.u[2] = g2 ? b2 : a2; pb.u[3] = g2 ? b3 : a3;
            #pragma unroll
            for (int nd = 0; nd < 4; ++nd) {
                int row = nd * 16 + q16;               // d row in Vt
                bf16x8 av = *(const bf16x8*)&Vt[row * 64 + ((kk * 4 + g) ^ (row & 7)) * 8];
                oacc[nd] = __builtin_amdgcn_mfma_f32_16x16x32_bf16(av, pb.v, oacc[nd], 0, 0, 0);
            }
        }
    }

    // ---- epilogue: normalize, store bf16 (d = nd*16 + g*4 + r)
    float inv = 1.f / lrow;
    size_t obase = (size_t)(b * T_ + qrow) * D_ + hoff + g * 4;
    #pragma unroll
    for (int nd = 0; nd < 4; ++nd) {
        ushort4 st;
        st.x = f2bf(oacc[nd][0] * inv); st.y = f2bf(oacc[nd][1] * inv);
        st.z = f2bf(oacc[nd][2] * inv); st.w = f2bf(oacc[nd][3] * inv);
        *(ushort4*)&out[obase + nd * 16] = st;
    }
}

// ---------------------------------------------------------------------------
// Fused residual-add + LayerNorm -> fp32 out (+ optional bf16 copy)
// ---------------------------------------------------------------------------
__global__ __launch_bounds__(256) void ln_kernel(const float* __restrict__ a,
                                                 const float* __restrict__ r,
                                                 const float* __restrict__ g,
                                                 const float* __restrict__ be,
                                                 float* __restrict__ out,
                                                 ushort_t* __restrict__ outbf)
{
    __shared__ float red[256], red2[256];
    int row = blockIdx.x;
    int tid = threadIdx.x;
    size_t base = (size_t)row * D_;
    float v0 = a[base + tid]       + r[base + tid];
    float v1 = a[base + tid + 256] + r[base + tid + 256];
    red[tid] = v0 + v1;
    red2[tid] = v0 * v0 + v1 * v1;
    __syncthreads();
    for (int st = 128; st > 0; st >>= 1) {
        if (tid < st) { red[tid] += red[tid + st]; red2[tid] += red2[tid + st]; }
        __syncthreads();
    }
    float mean = red[0] * (1.f / D_);
    float var  = red2[0] * (1.f / D_) - mean * mean;
    float rstd = rsqrtf(var + EPS_);
    float w0 = (v0 - mean) * rstd * g[tid]       + be[tid];
    float w1 = (v1 - mean) * rstd * g[tid + 256] + be[tid + 256];
    out[base + tid]       = w0;
    out[base + tid + 256] = w1;
    if (outbf) {
        outbf[base + tid]       = f2bf(w0);
        outbf[base + tid + 256] = f2bf(w1);
    }
}

// ---------------------------------------------------------------------------
// Workspace (float units, 6M floats = 24 MB):
//   y     ws+0     [M,D] fp32 residual
//   tmpA  ws+1M    [M,D] fp32 pre-LN
//   bfbig ws+2M    2M floats = 4M bf16: qkv(3M) | kv(2M)+qb(1M) | hbf(4M)
//   WtS   ws+4M    transposed bf16 weights (max 1M bf16)
//   ybf   ws+4.5M  bf16 y
//   xbf   ws+5M    bf16 x
//   abf   ws+5.5M  bf16 attention out
// ---------------------------------------------------------------------------
extern "C" void kernel_launch(void* const* d_in, const int* in_sizes, int n_in,
                              void* d_out, int out_size, void* d_ws, size_t ws_size,
                              hipStream_t stream)
{
    const float* x          = (const float*)d_in[0];
    const int*   y_tokens   = (const int*)  d_in[1];
    const float* self_mask  = (const float*)d_in[2];
    const float* cross_mask = (const float*)d_in[3];
    const float* emb        = (const float*)d_in[4];
    const float* Wqkv = (const float*)d_in[5];  const float* bqkv = (const float*)d_in[6];
    const float* Wo   = (const float*)d_in[7];  const float* bo   = (const float*)d_in[8];
    const float* Wkv  = (const float*)d_in[9];  const float* bkv  = (const float*)d_in[10];
    const float* Wq   = (const float*)d_in[11]; const float* bq   = (const float*)d_in[12];
    const float* Wco  = (const float*)d_in[13]; const float* bco  = (const float*)d_in[14];
    const float* W1   = (const float*)d_in[15]; const float* b1   = (const float*)d_in[16];
    const float* W2   = (const float*)d_in[17]; const float* b2   = (const float*)d_in[18];
    const float* g1   = (const float*)d_in[19]; const float* be1  = (const float*)d_in[20];
    const float* g2   = (const float*)d_in[21]; const float* be2  = (const float*)d_in[22];
    const float* g3   = (const float*)d_in[23]; const float* be3  = (const float*)d_in[24];

    float* ws = (float*)d_ws;
    const size_t MD = (size_t)M_ * D_;            // 1M floats
    float*    y    = ws;
    float*    tmpA = ws + MD;
    ushort_t* bfbig = (ushort_t*)(ws + 2 * MD);
    ushort_t* WtS  = (ushort_t*)(ws + 4 * MD);
    ushort_t* ybf  = (ushort_t*)(ws + 4 * MD + MD / 2);
    ushort_t* xbf  = (ushort_t*)(ws + 5 * MD);
    ushort_t* abf  = (ushort_t*)(ws + 5 * MD + MD / 2);

    ushort_t* qkvbf = bfbig;                      // [M][3D]
    ushort_t* kvbf  = bfbig;                      // [M][2D]
    ushort_t* qbbf  = bfbig + (size_t)M_ * 2 * D_;// [M][D]
    ushort_t* hbf   = bfbig;                      // [M][F]

    embed_kernel<<<(M_ * D_) / 256, 256, 0, stream>>>(y_tokens, emb, y, ybf);
    cvt_bf16_kernel<<<(M_ * D_) / 1024, 256, 0, stream>>>(x, xbf);

    for (int l = 0; l < L_; ++l) {
        const float* Wqkv_l = Wqkv + (size_t)l * D_ * 3 * D_;
        const float* bqkv_l = bqkv + (size_t)l * 3 * D_;
        const float* Wo_l   = Wo   + (size_t)l * D_ * D_;
        const float* bo_l   = bo   + (size_t)l * D_;
        const float* Wkv_l  = Wkv  + (size_t)l * D_ * 2 * D_;
        const float* bkv_l  = bkv  + (size_t)l * 2 * D_;
        const float* Wq_l   = Wq   + (size_t)l * D_ * D_;
        const float* bq_l   = bq   + (size_t)l * D_;
        const float* Wco_l  = Wco  + (size_t)l * D_ * D_;
        const float* bco_l  = bco  + (size_t)l * D_;
        const float* W1_l   = W1   + (size_t)l * D_ * F_;
        const float* b1_l   = b1   + (size_t)l * F_;
        const float* W2_l   = W2   + (size_t)l * F_ * D_;
        const float* b2_l   = b2   + (size_t)l * D_;

        // ---- self-attention block
        transpose_cvt_kernel<<<dim3(3 * D_ / 64, D_ / 64), 256, 0, stream>>>(
            Wqkv_l, WtS, D_, 3 * D_);
        gemm_bf16_kernel<2><<<dim3(3 * D_ / 128, M_ / 128), 256, 0, stream>>>(
            ybf, WtS, bqkv_l, qkvbf, M_, 3 * D_, D_);
        fattn_mfma_kernel<<<dim3(H_, T_ / 64, B_), 256, 0, stream>>>(
            qkvbf, 3 * D_, 0, qkvbf, 3 * D_, D_, qkvbf, 3 * D_, 2 * D_, self_mask, abf);
        transpose_cvt_kernel<<<dim3(D_ / 64, D_ / 64), 256, 0, stream>>>(
            Wo_l, WtS, D_, D_);
        gemm_bf16_kernel<0><<<dim3(D_ / 128, M_ / 128), 256, 0, stream>>>(
            abf, WtS, bo_l, tmpA, M_, D_, D_);
        ln_kernel<<<M_, 256, 0, stream>>>(tmpA, y, g1 + l * D_, be1 + l * D_, y, ybf);

        // ---- cross-attention block
        transpose_cvt_kernel<<<dim3(2 * D_ / 64, D_ / 64), 256, 0, stream>>>(
            Wkv_l, WtS, D_, 2 * D_);
        gemm_bf16_kernel<2><<<dim3(2 * D_ / 128, M_ / 128), 256, 0, stream>>>(
            xbf, WtS, bkv_l, kvbf, M_, 2 * D_, D_);
        transpose_cvt_kernel<<<dim3(D_ / 64, D_ / 64), 256, 0, stream>>>(
            Wq_l, WtS, D_, D_);
        gemm_bf16_kernel<2><<<dim3(D_ / 128, M_ / 128), 256, 0, stream>>>(
            ybf, WtS, bq_l, qbbf, M_, D_, D_);
        fattn_mfma_kernel<<<dim3(H_, T_ / 64, B_), 256, 0, stream>>>(
            qbbf, D_, 0, kvbf, 2 * D_, 0, kvbf, 2 * D_, D_, cross_mask, abf);
        transpose_cvt_kernel<<<dim3(D_ / 64, D_ / 64), 256, 0, stream>>>(
            Wco_l, WtS, D_, D_);
        gemm_bf16_kernel<0><<<dim3(D_ / 128, M_ / 128), 256, 0, stream>>>(
            abf, WtS, bco_l, tmpA, M_, D_, D_);
        ln_kernel<<<M_, 256, 0, stream>>>(tmpA, y, g2 + l * D_, be2 + l * D_, y, ybf);

        // ---- feed-forward block
        transpose_cvt_kernel<<<dim3(F_ / 64, D_ / 64), 256, 0, stream>>>(
            W1_l, WtS, D_, F_);
        gemm_bf16_kernel<1><<<dim3(F_ / 128, M_ / 128), 256, 0, stream>>>(
            ybf, WtS, b1_l, hbf, M_, F_, D_);
        transpose_cvt_kernel<<<dim3(D_ / 64, F_ / 64), 256, 0, stream>>>(
            W2_l, WtS, F_, D_);
        gemm_bf16_kernel<0><<<dim3(D_ / 128, M_ / 128), 256, 0, stream>>>(
            hbf, WtS, b2_l, tmpA, M_, D_, F_);
        float* lnout = (l == L_ - 1) ? (float*)d_out : y;
        ln_kernel<<<M_, 256, 0, stream>>>(tmpA, y, g3 + l * D_, be3 + l * D_, lnout, ybf);
    }
}